// Round 18
// baseline (18.444 us; speedup 1.0000x reference)
//
#include <hip/hip_runtime.h>
#include <hip/hip_bf16.h>

#define RAD 5
#define DIL 6
#define KS 11            // 2*RAD+1
#define PADW 30          // RAD*DIL
#define TOPK 8
#define TILEW 192        // 188 used cols (128 + 60 halo), padded
#define EXSTR 9          // exchange stride (odd -> 2-way banks, free)

// Problem shape (fixed by reference setup_inputs)
constexpr int B = 2;
constexpr int H = 256;
constexpr int W = 512;
constexpr int HW = H * W;
constexpr int NBLK = 2048;                 // B*H*(W/128)
constexpr int NPART = NBLK * 4;            // one partial per wave = 8192
constexpr double TOTAL_CNT = (double)B * H * W * TOPK;   // 2,097,152

// ---------------------------------------------------------------------------
// Straight-line sorting-network primitives over NAMED registers.
// ---------------------------------------------------------------------------
#define CE(a,b) { const unsigned _l = min(a,b); const unsigned _h = max(a,b); (a)=_l; (b)=_h; }

// Batcher odd-even mergesort for 8 (19 CE), ascending. Proven exact (r2..r17).
#define SORT8M(k0,k1,k2,k3,k4,k5,k6,k7) \
  CE(k0,k1) CE(k2,k3) CE(k4,k5) CE(k6,k7) \
  CE(k0,k2) CE(k1,k3) CE(k4,k6) CE(k5,k7) \
  CE(k1,k2) CE(k5,k6) \
  CE(k0,k4) CE(k1,k5) CE(k2,k6) CE(k3,k7) \
  CE(k2,k4) CE(k3,k5) \
  CE(k1,k2) CE(k3,k4) CE(k5,k6)

// b (sorted asc) := sorted lowest-8 of union(b, c) where c sorted asc.
#define MERGELOW8M(b0,b1,b2,b3,b4,b5,b6,b7) { \
  unsigned t0=min(b0,c7), t1=min(b1,c6), t2=min(b2,c5), t3=min(b3,c4); \
  unsigned t4=min(b4,c3), t5=min(b5,c2), t6=min(b6,c1), t7=min(b7,c0); \
  CE(t0,t4) CE(t1,t5) CE(t2,t6) CE(t3,t7) \
  CE(t0,t2) CE(t1,t3) CE(t4,t6) CE(t5,t7) \
  CE(t0,t1) CE(t2,t3) CE(t4,t5) CE(t6,t7) \
  b0=t0; b1=t1; b2=t2; b3=t3; b4=t4; b5=t5; b6=t6; b7=t7; }

// Raw tap read at compile-time tap T: 32-bit dword row base + compile-time
// dword offset (KX*6 <= 60) -> ds_read2_b32-mergeable. OOB taps read the
// staged 1.0f sentinel (ranks after all votes < 1.0).
template<int T>
__device__ __forceinline__ unsigned rawtap(const float (&vt)[KS * TILEW],
                                           const unsigned (&rbase)[KS]) {
    constexpr int KY = T / KS;
    constexpr int KX = T % KS;
    return __float_as_uint(vt[rbase[KY] + KX * DIL]);
}

// Pair key: (min of raws) masked, pair index in low 7 bits.
#define PAIRK(P) ((min(rawtap<2*(P)>(vt, rbase), rawtap<2*(P)+1>(vt, rbase)) & 0xFFFFFF80u) | (unsigned)(P))

#define LOADG8(PB) \
  c0 = PAIRK(PB+0); c1 = PAIRK(PB+1); c2 = PAIRK(PB+2); c3 = PAIRK(PB+3); \
  c4 = PAIRK(PB+4); c5 = PAIRK(PB+5); c6 = PAIRK(PB+6); c7 = PAIRK(PB+7); \
  SORT8M(c0,c1,c2,c3,c4,c5,c6,c7)

// Stage-C member key for runtime tap t (<=121): sentinel tile -> no bounds
// test. t=121 (partner of self-paired 120) clamped for address, discarded.
__device__ __forceinline__ unsigned member_key_lds(const float (&vt)[KS * TILEW],
                                                   int p, unsigned t) {
    const unsigned tc = min(t, 120u);
    const int ky = (int)((tc * 373u) >> 12);     // floor(tc/11), exact
    const int kx = (int)tc - ky * KS;
    const unsigned raw = __float_as_uint(vt[ky * TILEW + p + kx * DIL]);
    return (raw & 0xFFFFFF80u) | tc;
}

#define REBUILD(BS, MA, MB) { \
  const unsigned _p = (BS) & 127u; \
  MA = member_key_lds(vt, p, _p * 2u); \
  const unsigned _mb = member_key_lds(vt, p, _p * 2u + 1u); \
  MB = (_p == 60u) ? 0xFFFFFFFFu : _mb; }

// One gathered loss term for selected key (replicate padding via clamp).
__device__ __forceinline__ float loss_term(const float* __restrict__ db,
                                           const float* __restrict__ sb,
                                           float dC, float sC,
                                           int h, int w, unsigned key) {
    const unsigned idx = key & 127u;
    const int ky = (int)((idx * 373u) >> 12);
    const int kx = (int)idx - ky * KS;
    const int y = min(max(h + ky * DIL - PADW, 0), H - 1);
    const int x = min(max(w + kx * DIL - PADW, 0), W - 1);
    const int nb = y * W + x;
    const float dN = db[nb];
    const float sN = sb[nb];
    const float dg = dC - dN;
    const float sg = sC - sN;
    const float dd = sg * __builtin_amdgcn_rcpf(fabsf(sg) + 1e-8f);
    const float a  = fmaxf(fabsf(dg) - 1.0f, 0.0f);
    const float m  = a * __builtin_amdgcn_rcpf(1.0f + a);
    const float dw = copysignf(m, dg);
    const float dv = __log2f(fmaf(sg, sg, 1.0f)) * 0.69314718056f;
    return fmaxf(-(dw * dd) * dv, 0.0f);
}

// ---------------------------------------------------------------------------
// 2-threads-per-pixel kernel: 2048 blocks x 256 threads; 128 pixels/block.
// Role 0 (tids 0-127, waves 0-1): pairs 0..29 (taps 0-59).
// Role 1 (tids 128-255, waves 2-3): pairs 30..60 (taps 60-120).
// -> 8192 waves total = 32 waves/CU (100% occupancy) vs r17's 16.
// Each role: sorted-8 of its pair-mins; LDS exchange; both roles compute the
// identical merged survivor set; role r rebuilds survivors r*4..r*4+3 (8
// members, sort8); exchange upper-half members; f_i = min(own_i,
// partner_{7-i}) i=0..3 is a DISJOINT+COMPLETE split of the exact bottom-8
// (role1's f0..3 == role0's f7..4); each thread gathers 4 loss terms.
// Two-kernel reduction retained (r14/r16: same-address atomic tails cost
// +28..46us; plain stores + tiny dispatch ~2-4us).
// ---------------------------------------------------------------------------
__global__ __launch_bounds__(256, 8) void lrl_main(
    const float* __restrict__ disp,
    const float* __restrict__ depth,
    const float* __restrict__ vote,
    float* __restrict__ partials)      // NPART floats, one per wave
{
    const int tid  = threadIdx.x;
    const int blk  = blockIdx.x;               // 0 .. NBLK-1
    const int row  = blk >> 2;                 // b*H + h
    const int q    = blk & 3;                  // quarter of the row
    const int b    = row >> 8;
    const int h    = row & (H - 1);
    const int p    = tid & 127;                // pixel within block
    const int role = tid >> 7;                 // 0/1, wave-aligned
    const int w    = (q << 7) + p;
    const int x0b  = (q << 7) - 30;            // tile col 0 -> global x

    const float* __restrict__ vb = vote  + b * HW;
    const float* __restrict__ db = depth + b * HW;
    const float* __restrict__ sb = disp  + b * HW;

    const float dC = db[h * W + w];
    const float sC = sb[h * W + w];

    // ---- Stage sentinel-halo tile: 11 rows x 188 cols (x-range w0-30 ..
    // w0+157); OOB x/y = 1.0f sentinel. float2 per thread, threads 0..95.
    __shared__ float    vt[KS * TILEW];
    __shared__ unsigned ex[2 * 128 * EXSTR];
#pragma unroll
    for (int ky = 0; ky < KS; ++ky) {
        const int y = h + ky * DIL - PADW;     // block-uniform
        if (tid < 96) {
            const int c2 = 2 * tid;
            const int x0 = x0b + c2;           // even; pair never straddles
            float2 v = make_float2(1.0f, 1.0f);
            if (((unsigned)y < (unsigned)H) & ((unsigned)x0 <= 510u))
                v = *(const float2*)(vb + y * W + x0);
            *(float2*)&vt[ky * TILEW + c2] = v;
        }
    }

    // Per-row 32-bit dword bases (constexpr-indexed -> registers).
    unsigned rbase[KS];
#pragma unroll
    for (int ky = 0; ky < KS; ++ky) rbase[ky] = ky * TILEW + p;

    __syncthreads();                           // A: tile ready

    // ---- Role-split selection: sorted low-8 of own pair keys --------------
    unsigned b0,b1,b2,b3,b4,b5,b6,b7, c0,c1,c2,c3,c4,c5,c6,c7;
    if (role == 0) {                           // pairs 0..29 (taps 0..59)
        LOADG8(0);
        b0=c0; b1=c1; b2=c2; b3=c3; b4=c4; b5=c5; b6=c6; b7=c7;
        LOADG8(8);  MERGELOW8M(b0,b1,b2,b3,b4,b5,b6,b7);
        LOADG8(16); MERGELOW8M(b0,b1,b2,b3,b4,b5,b6,b7);
        c0 = PAIRK(24); c1 = PAIRK(25); c2 = PAIRK(26);
        c3 = PAIRK(27); c4 = PAIRK(28); c5 = PAIRK(29);
        c6 = 0xFFFFFFFFu; c7 = 0xFFFFFFFFu;
        SORT8M(c0,c1,c2,c3,c4,c5,c6,c7);
        MERGELOW8M(b0,b1,b2,b3,b4,b5,b6,b7);
    } else {                                   // pairs 30..59 + tap120 (pair 60)
        LOADG8(30);
        b0=c0; b1=c1; b2=c2; b3=c3; b4=c4; b5=c5; b6=c6; b7=c7;
        LOADG8(38); MERGELOW8M(b0,b1,b2,b3,b4,b5,b6,b7);
        LOADG8(46); MERGELOW8M(b0,b1,b2,b3,b4,b5,b6,b7);
        c0 = PAIRK(54); c1 = PAIRK(55); c2 = PAIRK(56);
        c3 = PAIRK(57); c4 = PAIRK(58); c5 = PAIRK(59);
        c6 = (rawtap<120>(vt, rbase) & 0xFFFFFF80u) | 60u;   // self-paired
        c7 = 0xFFFFFFFFu;
        SORT8M(c0,c1,c2,c3,c4,c5,c6,c7);
        MERGELOW8M(b0,b1,b2,b3,b4,b5,b6,b7);
    }

    // ---- Exchange 1: sorted-8 across roles; both compute identical merge --
    unsigned* exh = &ex[(role * 128 + p) * EXSTR];
    unsigned* exp_ = &ex[(((role ^ 1) * 128) + p) * EXSTR];
    exh[0]=b0; exh[1]=b1; exh[2]=b2; exh[3]=b3;
    exh[4]=b4; exh[5]=b5; exh[6]=b6; exh[7]=b7;
    __syncthreads();                           // B
    c0=exp_[0]; c1=exp_[1]; c2=exp_[2]; c3=exp_[3];
    c4=exp_[4]; c5=exp_[5]; c6=exp_[6]; c7=exp_[7];
    MERGELOW8M(b0,b1,b2,b3,b4,b5,b6,b7);       // global survivors (both roles)

    // ---- Stage C: role r rebuilds survivors r*4..r*4+3 --------------------
    const unsigned s0 = role ? b4 : b0;
    const unsigned s1 = role ? b5 : b1;
    const unsigned s2 = role ? b6 : b2;
    const unsigned s3 = role ? b7 : b3;
    unsigned m0,m1,m2,m3,m4,m5,m6,m7;
    REBUILD(s0, m0, m1); REBUILD(s1, m2, m3);
    REBUILD(s2, m4, m5); REBUILD(s3, m6, m7);
    SORT8M(m0,m1,m2,m3,m4,m5,m6,m7);

    __syncthreads();                           // C: exch1 reads complete
    // ---- Exchange 2: upper-half members (only m4..m7 needed by partner) ---
    exh[0]=m4; exh[1]=m5; exh[2]=m6; exh[3]=m7;
    __syncthreads();                           // D
    const unsigned q4 = exp_[0], q5 = exp_[1], q6 = exp_[2], q7 = exp_[3];

    // ---- Stage D split: f_i = min(own_i, partner_{7-i}), i=0..3 -----------
    const unsigned f0 = min(m0, q7), f1 = min(m1, q6);
    const unsigned f2 = min(m2, q5), f3 = min(m3, q4);

    // ---- Gather 4 loss terms (global clamped loads, L2-resident) ----------
    float acc = loss_term(db, sb, dC, sC, h, w, f0)
              + loss_term(db, sb, dC, sC, h, w, f1)
              + loss_term(db, sb, dC, sC, h, w, f2)
              + loss_term(db, sb, dC, sC, h, w, f3);

    // ---- Wave reduce + per-wave partial store -----------------------------
#pragma unroll
    for (int off = 32; off > 0; off >>= 1)
        acc += __shfl_down(acc, off, 64);

    if ((tid & 63) == 0)
        partials[(blk << 2) | (tid >> 6)] = acc;
}

// ---------------------------------------------------------------------------
// Stage 2: deterministic final reduction of 8192 wave partials (f64 tree).
// ---------------------------------------------------------------------------
__global__ __launch_bounds__(256) void lrl_reduce(
    const float* __restrict__ partials, float* __restrict__ out)
{
    __shared__ double ssum[256];
    const float4* p4 = (const float4*)partials;   // 2048 float4s
    double s = 0.0;
#pragma unroll
    for (int i = 0; i < 8; ++i) {
        const float4 v = p4[threadIdx.x + i * 256];
        s += (double)v.x + (double)v.y + (double)v.z + (double)v.w;
    }
    ssum[threadIdx.x] = s;
    __syncthreads();
#pragma unroll
    for (int st = 128; st > 0; st >>= 1) {
        if (threadIdx.x < st) ssum[threadIdx.x] += ssum[threadIdx.x + st];
        __syncthreads();
    }
    if (threadIdx.x == 0) out[0] = (float)(ssum[0] / TOTAL_CNT);
}

extern "C" void kernel_launch(void* const* d_in, const int* in_sizes, int n_in,
                              void* d_out, int out_size, void* d_ws, size_t ws_size,
                              hipStream_t stream) {
    const float* disp  = (const float*)d_in[0];
    const float* depth = (const float*)d_in[1];
    const float* vote  = (const float*)d_in[2];
    float* out = (float*)d_out;

    float* partials = (float*)d_ws;        // NPART floats = 32 KB
    lrl_main<<<NBLK, 256, 0, stream>>>(disp, depth, vote, partials);
    lrl_reduce<<<1, 256, 0, stream>>>(partials, out);
}